// Round 16
// baseline (59.207 us; speedup 1.0000x reference)
//
#include <hip/hip_runtime.h>
#include <stdint.h>
#include <math.h>

#define N_PTS 8192
#define WPB   16
#define TPB   (WPB * 64)           // 1024
#define NBLK  (N_PTS / WPB)        // 512 blocks (1 round at 2 blocks/CU)
#define GRIDC 64
#define NCELL (GRIDC * GRIDC)
#define CW    (9.0f / 64.0f)
#define CINV  (64.0f / 9.0f)

typedef __fp16 h2 __attribute__((ext_vector_type(2)));
typedef uint32_t u32;

__device__ __forceinline__ u32 pksub(u32 a, u32 b) {
  u32 d;
  asm("v_pk_add_f16 %0, %1, %2 neg_lo:[0,1] neg_hi:[0,1]" : "=v"(d) : "v"(a), "v"(b));
  return d;
}
__device__ __forceinline__ float dot2u(u32 a, u32 b, float c) {
#if __has_builtin(__builtin_amdgcn_fdot2)
  return __builtin_amdgcn_fdot2(__builtin_bit_cast(h2, a), __builtin_bit_cast(h2, b), c, false);
#else
  h2 x = __builtin_bit_cast(h2, a), y = __builtin_bit_cast(h2, b);
  return fmaf((float)x.x, (float)y.x, fmaf((float)x.y, (float)y.y, c));
#endif
}
__device__ __forceinline__ u32 cvtpk(float a, float b) {
  return __builtin_bit_cast(u32, __builtin_amdgcn_cvt_pkrtz(a, b));
}
__device__ __forceinline__ int cellc(float v) {
  int c = (int)floorf((v + 4.5f) * CINV);
  return c < 0 ? 0 : (c > GRIDC - 1 ? GRIDC - 1 : c);
}

// ---------------- threefry2x32 (JAX partitionable random_bits) ----------------
__device__ __forceinline__ uint32_t rotl32(uint32_t x, int r) {
  return (x << r) | (x >> (32 - r));
}
__device__ __forceinline__ uint32_t threefry_bits(uint32_t idx) {
  const uint32_t k0 = 0u, k1 = 42u;
  const uint32_t k2c = k0 ^ k1 ^ 0x1BD11BDAu;
  uint32_t x0 = 0u, x1 = idx;
  x0 += k0; x1 += k1;
  x0 += x1; x1 = rotl32(x1, 13); x1 ^= x0;
  x0 += x1; x1 = rotl32(x1, 15); x1 ^= x0;
  x0 += x1; x1 = rotl32(x1, 26); x1 ^= x0;
  x0 += x1; x1 = rotl32(x1,  6); x1 ^= x0;
  x0 += k1; x1 += k2c + 1u;
  x0 += x1; x1 = rotl32(x1, 17); x1 ^= x0;
  x0 += x1; x1 = rotl32(x1, 29); x1 ^= x0;
  x0 += x1; x1 = rotl32(x1, 16); x1 ^= x0;
  x0 += x1; x1 = rotl32(x1, 24); x1 ^= x0;
  x0 += k2c; x1 += k0 + 2u;
  x0 += x1; x1 = rotl32(x1, 13); x1 ^= x0;
  x0 += x1; x1 = rotl32(x1, 15); x1 ^= x0;
  x0 += x1; x1 = rotl32(x1, 26); x1 ^= x0;
  x0 += x1; x1 = rotl32(x1,  6); x1 ^= x0;
  x0 += k0; x1 += k1 + 3u;
  x0 += x1; x1 = rotl32(x1, 17); x1 ^= x0;
  x0 += x1; x1 = rotl32(x1, 29); x1 ^= x0;
  x0 += x1; x1 = rotl32(x1, 16); x1 ^= x0;
  x0 += x1; x1 = rotl32(x1, 24); x1 ^= x0;
  x0 += k1; x1 += k2c + 4u;
  x0 += x1; x1 = rotl32(x1, 13); x1 ^= x0;
  x0 += x1; x1 = rotl32(x1, 15); x1 ^= x0;
  x0 += x1; x1 = rotl32(x1, 26); x1 ^= x0;
  x0 += x1; x1 = rotl32(x1,  6); x1 ^= x0;
  x0 += k2c; x1 += k0 + 5u;
  return x0 ^ x1;
}
__device__ __forceinline__ float erfinv_xla(float x) {
  float w = -log1pf(-x * x);
  float p;
  if (w < 5.0f) {
    w -= 2.5f;
    p = 2.81022636e-08f;
    p = fmaf(p, w, 3.43273939e-07f);
    p = fmaf(p, w, -3.5233877e-06f);
    p = fmaf(p, w, -4.39150654e-06f);
    p = fmaf(p, w, 0.00021858087f);
    p = fmaf(p, w, -0.00125372503f);
    p = fmaf(p, w, -0.00417768164f);
    p = fmaf(p, w, 0.246640727f);
    p = fmaf(p, w, 1.50140941f);
  } else {
    w = sqrtf(w) - 3.0f;
    p = -0.000200214257f;
    p = fmaf(p, w, 0.000100950558f);
    p = fmaf(p, w, 0.00134934322f);
    p = fmaf(p, w, -0.00367342844f);
    p = fmaf(p, w, 0.00573950773f);
    p = fmaf(p, w, -0.0076224613f);
    p = fmaf(p, w, 0.00943887047f);
    p = fmaf(p, w, 1.00167406f);
    p = fmaf(p, w, 2.83297682f);
  }
  return p * x;
}
__device__ __forceinline__ float jax_noise(uint32_t idx) {
  uint32_t bits = threefry_bits(idx);
  float uf = __uint_as_float((bits >> 9) | 0x3F800000u) - 1.0f;
  const float lo_u = -0.99999994f;
  float u = fmaxf(lo_u, fmaf(uf, 2.0f, lo_u));
  return 1.4142135623730951f * erfinv_xla(u) * 0.01f;
}

// ======= K1: single-block LDS-only build: hist + prefix + stats + cursor =======
__global__ __launch_bounds__(1024) void build1_kernel(const float* __restrict__ x,
                                                      float* __restrict__ stats,
                                                      u32* __restrict__ base,
                                                      u32* __restrict__ cursor) {
  __shared__ u32 baseL[NCELL];
  __shared__ u32 ssc[1024];
  __shared__ double sred[16][4];
  const int t = threadIdx.x;

#pragma unroll
  for (int k = 0; k < 4; ++k) baseL[t * 4 + k] = 0;
  __syncthreads();

  double s0 = 0, s1 = 0, q0 = 0, q1 = 0;
#pragma unroll
  for (int k = 0; k < 8; ++k) {
    float2 p = ((const float2*)x)[t * 8 + k];
    int cell = cellc(p.y) * GRIDC + cellc(p.x);
    atomicAdd(&baseL[cell], 1u);
    s0 += (double)p.x; s1 += (double)p.y;
    q0 += (double)p.x * (double)p.x; q1 += (double)p.y * (double)p.y;
  }
#pragma unroll
  for (int m = 1; m < 64; m <<= 1) {
    s0 += __shfl_xor(s0, m); s1 += __shfl_xor(s1, m);
    q0 += __shfl_xor(q0, m); q1 += __shfl_xor(q1, m);
  }
  if ((t & 63) == 0) {
    sred[t >> 6][0] = s0; sred[t >> 6][1] = s1;
    sred[t >> 6][2] = q0; sred[t >> 6][3] = q1;
  }
  __syncthreads();

  u32 c0 = baseL[t * 4], c1 = baseL[t * 4 + 1], c2 = baseL[t * 4 + 2], c3 = baseL[t * 4 + 3];
  u32 sum = c0 + c1 + c2 + c3;
  ssc[t] = sum;
  __syncthreads();
  for (int off = 1; off < 1024; off <<= 1) {
    u32 v = (t >= off) ? ssc[t - off] : 0u;
    __syncthreads();
    ssc[t] += v;
    __syncthreads();
  }
  u32 run = ssc[t] - sum;  // exclusive
  u32 b0 = run, b1 = run + c0, b2 = b1 + c1, b3 = b2 + c2;
  base[t * 4] = b0;   base[t * 4 + 1] = b1;   base[t * 4 + 2] = b2;   base[t * 4 + 3] = b3;
  cursor[t * 4] = b0; cursor[t * 4 + 1] = b1; cursor[t * 4 + 2] = b2; cursor[t * 4 + 3] = b3;
  if (t == 1023) base[NCELL] = N_PTS;
  if (t == 0) {
    double a0 = 0, a1 = 0, d0 = 0, d1 = 0;
    for (int k = 0; k < 16; ++k) {
      a0 += sred[k][0]; a1 += sred[k][1]; d0 += sred[k][2]; d1 += sred[k][3];
    }
    double n = (double)N_PTS, m0 = a0 / n, m1 = a1 / n;
    stats[0] = (float)m0; stats[1] = (float)m1;
    stats[2] = (float)sqrt((d0 - n * m0 * m0) / (n - 1.0));
    stats[3] = (float)sqrt((d1 - n * m1 * m1) / (n - 1.0));
  }
}

// ======= K2: place (parallel global scatter) =======
__global__ __launch_bounds__(256) void place_kernel(const float* __restrict__ x,
                                                    u32* __restrict__ cursor,
                                                    u32* __restrict__ tmp_pt,
                                                    u32* __restrict__ tmp_ci) {
  int i = blockIdx.x * 256 + threadIdx.x;
  float2 p = ((const float2*)x)[i];
  int cell = cellc(p.y) * GRIDC + cellc(p.x);
  u32 slot = atomicAdd(&cursor[cell], 1u);
  tmp_pt[slot] = cvtpk(p.x, p.y);
  tmp_ci[slot] = ((u32)cell << 13) | (u32)i;
}

// ======= K3: stable rank within cell (parallel global gather) =======
__global__ __launch_bounds__(256) void rank_kernel(const u32* __restrict__ base,
                                                   const u32* __restrict__ tmp_pt,
                                                   const u32* __restrict__ tmp_ci,
                                                   u32* __restrict__ spt,
                                                   unsigned short* __restrict__ sidx) {
  int s = blockIdx.x * 256 + threadIdx.x;
  u32 v = tmp_ci[s];
  u32 cell = v >> 13, i = v & 8191u;
  u32 lo = base[cell], hi = base[cell + 1];
  u32 rank = 0;
  for (u32 j = lo; j < hi; ++j) rank += ((tmp_ci[j] & 8191u) < i) ? 1u : 0u;
  u32 d = lo + rank;
  spt[d] = tmp_pt[s];
  sidx[d] = (unsigned short)i;
}

// ======= K4: main — contiguous ROW-SLAB scans over LDS-resident sorted points =======
__global__ __launch_bounds__(TPB, 2) void main_kernel(const float* __restrict__ x,
                                                      const float* __restrict__ stats,
                                                      const u32* __restrict__ base,
                                                      const u32* __restrict__ spt,
                                                      const unsigned short* __restrict__ sidx,
                                                      float* __restrict__ hbuf) {
  __shared__ u32 sptL[N_PTS];       // 32 KB
  __shared__ u32 baseL[NCELL + 1];  // 16.4 KB
  const int t = threadIdx.x;
  const int w = t >> 6;
  const int s = t & 63;

#pragma unroll
  for (int k = 0; k < 2; ++k)
    ((uint4*)sptL)[k * TPB + t] = ((const uint4*)spt)[k * TPB + t];
#pragma unroll
  for (int k = 0; k < 4; ++k) baseL[k * TPB + t] = base[k * TPB + t];
  if (t == 0) baseL[NCELL] = N_PTS;
  __syncthreads();

  // strided assignment: spatially-clustered rows spread across blocks
  const int p = w * NBLK + blockIdx.x;
  const int orig = (int)sidx[p];
  const float2 xg = ((const float2*)x)[orig];
  const u32 xihu = cvtpk(xg.x, xg.y);
  const int cy = cellc(xg.y);
  const float INF = 3.402823466e+38f;
  const uint4* v4 = (const uint4*)sptL;

  // ---- pre-size y-slab from row sums (baseL) ----
  int cyl, cyh;
  {
    int ry = 2;
    for (;;) {
      cyl = max(cy - ry, 0); cyh = min(cy + ry, GRIDC - 1);
      u32 cnt = baseL[(cyh + 1) << 6] - baseL[cyl << 6];
      if (cnt >= 192u || (cyl == 0 && cyh == GRIDC - 1)) break;
      ry <<= 1;
    }
  }

  // ---- phase A: contiguous slab scan, per-lane cap-8 lists, exact-rank + y-verify ----
  float d2k;
  for (;;) {
    float r0 = INF, r1 = INF, r2 = INF, r3 = INF, r4 = INF, r5 = INF, r6 = INF, r7 = INF;
    u32 lo = baseL[cyl << 6];
    u32 hi = baseL[(cyh + 1) << 6];
#define INS8(d2)                      \
    r7 = fminf(fmaxf(r6, d2), r7);    \
    r6 = fminf(fmaxf(r5, d2), r6);    \
    r5 = fminf(fmaxf(r4, d2), r5);    \
    r4 = fminf(fmaxf(r3, d2), r4);    \
    r3 = fminf(fmaxf(r2, d2), r3);    \
    r2 = fminf(fmaxf(r1, d2), r2);    \
    r1 = fminf(fmaxf(r0, d2), r1);    \
    r0 = fminf(r0, d2);
#define DQ4(q)                                       \
    { float da, db, dc, dd;                          \
      { u32 e = pksub(xihu, q.x); da = dot2u(e, e, 0.0f); } \
      { u32 e = pksub(xihu, q.y); db = dot2u(e, e, 0.0f); } \
      { u32 e = pksub(xihu, q.z); dc = dot2u(e, e, 0.0f); } \
      { u32 e = pksub(xihu, q.w); dd = dot2u(e, e, 0.0f); } \
      INS8(da) INS8(db) INS8(dc) INS8(dd) }
    {
      u32 vlo = lo >> 2;
      u32 vhi = (hi + 3u) >> 2;  // over-scan <=3 pts each side: still real points, valid
      u32 vi = vlo + (u32)s;
      for (; vi + 64u < vhi; vi += 128u) {  // 2 independent b128 loads per iter
        uint4 a = v4[vi];
        uint4 b = v4[vi + 64u];
        DQ4(a) DQ4(b)
      }
      if (vi < vhi) { uint4 a = v4[vi]; DQ4(a) }
    }
#undef DQ4
#undef INS8
    // exact rank-32 over 64 sorted cap-8 lists (f16-bit binary search)
    u32 b0 = (u32)__builtin_bit_cast(unsigned short, (__fp16)r0);
    u32 b1 = (u32)__builtin_bit_cast(unsigned short, (__fp16)r1);
    u32 b2 = (u32)__builtin_bit_cast(unsigned short, (__fp16)r2);
    u32 b3 = (u32)__builtin_bit_cast(unsigned short, (__fp16)r3);
    u32 b4 = (u32)__builtin_bit_cast(unsigned short, (__fp16)r4);
    u32 b5 = (u32)__builtin_bit_cast(unsigned short, (__fp16)r5);
    u32 b6 = (u32)__builtin_bit_cast(unsigned short, (__fp16)r6);
    u32 b7 = (u32)__builtin_bit_cast(unsigned short, (__fp16)r7);
    u32 blo = 0u, bhi = 0x7C01u;
    for (int it = 0; it < 15; ++it) {
      u32 mid = (blo + bhi) >> 1;
      int c = __popcll(__ballot(b0 < mid)) + __popcll(__ballot(b1 < mid)) +
              __popcll(__ballot(b2 < mid)) + __popcll(__ballot(b3 < mid)) +
              __popcll(__ballot(b4 < mid)) + __popcll(__ballot(b5 < mid)) +
              __popcll(__ballot(b6 < mid)) + __popcll(__ballot(b7 < mid));
      bool ge = (c >= 32);
      bhi = ge ? mid : bhi;
      blo = ge ? blo : mid;
    }
    unsigned short v32 = (unsigned short)(bhi - 1u);
    d2k = (float)__builtin_bit_cast(__fp16, v32);

    // verify: x-dimension is complete, so only y-margins matter
    float d32 = sqrtf(d2k) + 1e-2f;
    float myl = (cyl > 0) ? xg.y - (-4.5f + cyl * CW) : 1e9f;
    float myh = (cyh < GRIDC - 1) ? (-4.5f + (cyh + 1) * CW) - xg.y : 1e9f;
    if (d32 <= fminf(myl, myh)) break;
    if (cyl == 0 && cyh == GRIDC - 1) break;  // full set scanned: exact
    int ny = cyh - cyl + 1;
    cyl = max(cyl - ny, 0); cyh = min(cyh + ny, GRIDC - 1);
  }

  const float den = fmaf(2.0f, d2k, 1e-8f);
  const float nc1 = -1.4426950408889634f / den;  // w_scaled = 2^(10 + nc1*d)
  const float dcut = 9.704f * den;               // cut at scaled weight 2^-4

  // ---- phase B: contiguous slab scan, weight sums ----
  float sw = 0.f, swx = 0.f, swy = 0.f;
  {
    const int byl = cellc(xg.y - dcut), byh = cellc(xg.y + dcut);
    u32 lo = baseL[byl << 6];
    u32 hi = baseL[(byh + 1) << 6];
#define WACC(qp)                                                     \
    {                                                                \
      u32 e = pksub(xihu, qp);                                       \
      float d = __builtin_amdgcn_sqrtf(dot2u(e, e, 0.0f));           \
      float wgt = __builtin_amdgcn_exp2f(fmaf(nc1, d, 10.0f));       \
      h2 ph = __builtin_bit_cast(h2, qp);                            \
      sw += wgt;                                                     \
      swx = fmaf(wgt, (float)ph.x, swx);                             \
      swy = fmaf(wgt, (float)ph.y, swy);                             \
    }
    u32 vlo = lo >> 2;
    u32 vhi = (hi + 3u) >> 2;  // over-scan: extra REAL points, strictly more accurate
    u32 vi = vlo + (u32)s;
    for (; vi + 64u < vhi; vi += 128u) {
      uint4 a = v4[vi];
      uint4 b = v4[vi + 64u];
      WACC(a.x) WACC(a.y) WACC(a.z) WACC(a.w)
      WACC(b.x) WACC(b.y) WACC(b.z) WACC(b.w)
    }
    if (vi < vhi) { uint4 a = v4[vi]; WACC(a.x) WACC(a.y) WACC(a.z) WACC(a.w) }
#undef WACC
  }
#pragma unroll
  for (int m = 1; m < 64; m <<= 1) {
    sw  += __shfl_xor(sw,  m);
    swx += __shfl_xor(swx, m);
    swy += __shfl_xor(swy, m);
  }

  if (s < 2) {
    const float mean = stats[s];
    float inv   = 1.0f / (sw + 1e-8f);               // 2^10 scaling cancels in drift
    float drift = (s == 0 ? swx : swy) * inv - mean;
    float xcv   = (s == 0 ? xg.x : xg.y) - mean;
    uint32_t idx = 2u * (uint32_t)orig + (uint32_t)s;
    hbuf[idx] = fmaf(0.5f, drift - xcv, xcv) + jax_noise(idx);
  }
}

// ======= K5: every block reduces hbuf (deterministic) + writes scaled slice =======
__global__ __launch_bounds__(256) void scalefinal_kernel(const float* __restrict__ stats,
                                                         const float* __restrict__ hbuf,
                                                         float* __restrict__ out) {
  __shared__ double red[256][4];
  __shared__ float sc[2];
  const int t = threadIdx.x;
  double s0 = 0, s1 = 0, q0 = 0, q1 = 0;
#pragma unroll
  for (int k = 0; k < 32; ++k) {
    float2 v = ((const float2*)hbuf)[t + k * 256];
    s0 += (double)v.x; s1 += (double)v.y;
    q0 += (double)v.x * (double)v.x; q1 += (double)v.y * (double)v.y;
  }
  red[t][0] = s0; red[t][1] = s1; red[t][2] = q0; red[t][3] = q1;
  __syncthreads();
  for (int st = 128; st > 0; st >>= 1) {
    if (t < st) {
      red[t][0] += red[t + st][0]; red[t][1] += red[t + st][1];
      red[t][2] += red[t + st][2]; red[t][3] += red[t + st][3];
    }
    __syncthreads();
  }
  if (t < 2) {
    double n = (double)N_PTS;
    double m = red[0][t] / n;
    double v = (red[0][2 + t] - n * m * m) / (n - 1.0);
    sc[t] = stats[2 + t] / ((float)sqrt(v) + 1e-8f);
  }
  __syncthreads();
  int i = blockIdx.x * 256 + t;
  int d = i & 1;
  out[i] = fmaf(hbuf[i], sc[d], stats[d]);
}

extern "C" void kernel_launch(void* const* d_in, const int* in_sizes, int n_in,
                              void* d_out, int out_size, void* d_ws, size_t ws_size,
                              hipStream_t stream) {
  const float* x = (const float*)d_in[0];
  float* out = (float*)d_out;
  char* W = (char*)d_ws;
  float* stats = (float*)W;                               // 16 B
  u32* base   = (u32*)(W + 128);                          // 4097 u32
  u32* cursor = (u32*)(W + 16640);                        // 4096 u32
  unsigned short* sidx = (unsigned short*)(W + 33152);    // 8192 u16
  u32* tmp_pt = (u32*)(W + 49536);                        // 8192 u32
  u32* tmp_ci = (u32*)(W + 82304);                        // 8192 u32
  u32* spt    = (u32*)(W + 115072);                       // 8192 u32; ends 147840
  float* hbuf = (float*)(W + 49536);                      // overlays tmp (dead after rank)

  build1_kernel<<<1, 1024, 0, stream>>>(x, stats, base, cursor);
  place_kernel<<<N_PTS / 256, 256, 0, stream>>>(x, cursor, tmp_pt, tmp_ci);
  rank_kernel<<<N_PTS / 256, 256, 0, stream>>>(base, tmp_pt, tmp_ci, spt, sidx);
  main_kernel<<<NBLK, TPB, 0, stream>>>(x, stats, base, spt, sidx, hbuf);
  scalefinal_kernel<<<16384 / 256, 256, 0, stream>>>(stats, hbuf, out);
}